// Round 7
// baseline (495.183 us; speedup 1.0000x reference)
//
#include <hip/hip_runtime.h>
#include <math.h>

#define D_MODEL 2048
#define NEXP    64
#define NROWS   32768
#define NSUB    4                  // in-block K splits
#define KSUB    (D_MODEL / NSUB)   // 512 ks per sub
#define BM      64                 // rows per block
#define BKW     32                 // ks per staged W chunk
#define NCH     (KSUB / BKW)       // 16 chunks per sub
#define NG      (BKW / 4)          // 8 granules (16B) per chunk

// async global->LDS, 16B per lane; LDS dest = wave-uniform base + lane*16
__device__ __forceinline__ void stage16(const float* gsrc, void* lds_base) {
    __builtin_amdgcn_global_load_lds(
        (const __attribute__((address_space(1))) void*)gsrc,
        (__attribute__((address_space(3))) void*)lds_base,
        16, 0, 0);
}

// Block = 512 thr = 4 K-subs x 128 thr; sub s covers k in [512s,512s+512).
// 8x4 register tile (rg=row-group 0..7, eg=expert-group 0..15): live set
// acc32+xv32+wv16+ptrs ~110 regs -> fits the 128-VGPR cap the allocator
// enforces (r5/r6: bigger manual live sets -> 4-7MB scratch). BM=64 ->
// grid 512 -> 2 blocks/CU = 16 waves/CU (4/SIMD) for latency hiding;
// __launch_bounds__(512,4) pins VGPR<=128 which is exactly that occupancy.
// x: DIRECT global (16 dup eg-lanes merge in TA; each granule fetched once
// per block). W: LDS via global_load_lds, 4 b128/g-step -> ~41us LDS pipe
// (flat 12cyc/b128, calibrated r0). Partials reduced deterministically.
__global__ __launch_bounds__(512, 4) void router_kernel(
    const float* __restrict__ x,      // [NROWS, D_MODEL]
    const float* __restrict__ gw,     // [NEXP, D_MODEL]
    const float* __restrict__ bias,   // [NEXP]
    float* __restrict__ out)          // [NROWS*2 weights][NROWS*2 idx-as-float]
{
    __shared__ alignas(16) float4 ws[NSUB][2][NG][NEXP]; // 32 KB W chunks
    __shared__ float logits[BM][NEXP + 1];               // 16.6 KB, 65-stride

    const int t    = threadIdx.x;
    const int u    = t & 127;          // thread within sub
    const int sub  = t >> 7;           // K-split 0..3
    const int eg   = u & 15;           // expert group (16 contiguous lanes dup)
    const int rg   = u >> 4;           // row group 0..7 (8 rows each)
    const int w2   = u >> 6;           // wave within sub 0..1
    const int lane = t & 63;           // staging: lane = expert index
    const int r0   = blockIdx.x * BM;
    const int k0   = sub * KSUB;

    // 8 row pointers, advanced by BKW per chunk; inner offset g*16B folds
    // into the 13-bit immediate (<=112B)
    const float* xr[8];
#pragma unroll
    for (int i = 0; i < 8; ++i)
        xr[i] = x + (size_t)(r0 + rg * 8 + i) * D_MODEL + k0;

    float acc[8][4];
#pragma unroll
    for (int i = 0; i < 8; ++i)
#pragma unroll
        for (int j = 0; j < 4; ++j) acc[i][j] = 0.f;

    // prologue: stage chunk 0 -> buf 0 (per sub: 2 waves x 4 granule-rows;
    // LDS [gk][lane] <- W[lane][k0 + gk*4 ..+4))
#pragma unroll
    for (int q = 0; q < 4; ++q) {
        const int gk = w2 * 4 + q;
        stage16(gw + (size_t)lane * D_MODEL + k0 + gk * 4, &ws[sub][0][gk][0]);
    }
    __syncthreads();

    for (int c = 0; c < NCH; ++c) {
        const int cur = c & 1;
        if (c + 1 < NCH) {   // async-stage next chunk; drained by end barrier
#pragma unroll
            for (int q = 0; q < 4; ++q) {
                const int gk = w2 * 4 + q;
                stage16(gw + (size_t)lane * D_MODEL + k0 + (c + 1) * BKW + gk * 4,
                        &ws[sub][cur ^ 1][gk][0]);
            }
        }
#pragma unroll
        for (int g = 0; g < NG; ++g) {
            // 8 rows x 4 ks direct from global (4 distinct lines/instr,
            // 16x lane-dup merged in TA; imm offsets)
            float4 xv[8];
#pragma unroll
            for (int i = 0; i < 8; ++i)
                xv[i] = *(const float4*)(xr[i] + g * 4);
            // 4 experts x 4 ks from LDS (16 distinct 16B -> 2-way bank, free)
            float4 wv[4];
#pragma unroll
            for (int j = 0; j < 4; ++j)
                wv[j] = ws[sub][cur][g][j * 16 + eg];
#pragma unroll
            for (int i = 0; i < 8; ++i) {
#pragma unroll
                for (int j = 0; j < 4; ++j) {
                    acc[i][j] = fmaf(xv[i].x, wv[j].x, acc[i][j]);
                    acc[i][j] = fmaf(xv[i].y, wv[j].y, acc[i][j]);
                    acc[i][j] = fmaf(xv[i].z, wv[j].z, acc[i][j]);
                    acc[i][j] = fmaf(xv[i].w, wv[j].w, acc[i][j]);
                }
            }
        }
#pragma unroll
        for (int i = 0; i < 8; ++i) xr[i] += BKW;   // advance one chunk
        __syncthreads();   // readers done with buf cur; next stage complete
    }

    // deterministic in-block K-reduction: sub 0 writes, subs 1..3 accumulate
    for (int s = 0; s < NSUB; ++s) {
        if (sub == s) {
            if (s == 0) {
#pragma unroll
                for (int i = 0; i < 8; ++i)
#pragma unroll
                    for (int j = 0; j < 4; ++j)
                        logits[rg * 8 + i][j * 16 + eg] = acc[i][j];
            } else {
#pragma unroll
                for (int i = 0; i < 8; ++i)
#pragma unroll
                    for (int j = 0; j < 4; ++j)
                        logits[rg * 8 + i][j * 16 + eg] += acc[i][j];
            }
        }
        __syncthreads();
    }

    // epilogue: one thread per row (t < 64), identical to verified baseline
    if (t < BM) {
        const int row = r0 + t;
        float m1 = -INFINITY, m2 = -INFINITY;
        int   e1 = 0, e2 = 0;
        for (int e = 0; e < NEXP; ++e) {
            const float l = logits[t][e] + bias[e];
            if (l > m1) { m2 = m1; e2 = e1; m1 = l; e1 = e; }
            else if (l > m2) { m2 = l; e2 = e; }
        }
        float z = 0.f;
        for (int e = 0; e < NEXP; ++e)
            z += expf(logits[t][e] + bias[e] - m1);
        const float p2    = expf(m2 - m1);
        const float denom = (1.f + p2) + 1e-8f * z;
        out[row * 2 + 0] = 1.f / denom;
        out[row * 2 + 1] = p2 / denom;
        float* oidx = out + 2 * NROWS;
        oidx[row * 2 + 0] = (float)e1;
        oidx[row * 2 + 1] = (float)e2;
    }
}

extern "C" void kernel_launch(void* const* d_in, const int* in_sizes, int n_in,
                              void* d_out, int out_size, void* d_ws, size_t ws_size,
                              hipStream_t stream) {
    const float* x    = (const float*)d_in[0];   // [32768, 2048]
    const float* gw   = (const float*)d_in[1];   // [64, 2048]
    const float* bias = (const float*)d_in[2];   // [64]
    float* out = (float*)d_out;                  // 131072 floats
    (void)in_sizes; (void)n_in; (void)out_size; (void)d_ws; (void)ws_size;

    dim3 grid(NROWS / BM);   // 512 blocks -> 2 blocks/CU, 16 waves/CU
    dim3 block(512);         // 8 waves = 4 subs x 2 waves
    router_kernel<<<grid, block, 0, stream>>>(x, gw, bias, out);
}